// Round 6
// baseline (87.522 us; speedup 1.0000x reference)
//
#include <hip/hip_runtime.h>
#include <math.h>

// GeometricEmbedding: B=4, N=M=3000, d_model=2, sigma_d=1.0
// out[0..12000) float2 = p0[i] * (sum_m sin d, sum_m cos d)
// out[12000..24000)    = p1[i] * (sum_n sin d, sum_n cos d)
// d = sqrt(max(2 - 2*<p0,p1>, 0))
//
// R5 post-mortem: pair-once rotation structures (bpermute R4, DPP R5) both
// stall ~3x above issue floor for unknown reasons. Two-sided streaming (R2)
// behaved predictably: 87 cyc/step vs 52 floor, stalls = serialized loads
// (VGPR=16). This version: two-sided, 8-wide explicit load batches (all in
// named regs, immediate-offset loads), 4 independent acc pairs, constants
// folded so per-step = 2 fma + max + sqrt + sin + cos + 2 add = 34 cyc.
// Single kernel, direct output, no ws/atomics/second dispatch.

#define GB 4
#define GN 3000
#define K2   0.025330295910584444f   // (1/2pi)^2
#define C2   0.050660591821168888f   // 2*(1/2pi)^2

__device__ __forceinline__ void acc2(float2 q, float ax, float ay,
                                     float& s, float& c) {
    float t = fmaf(ax, q.x, fmaf(ay, q.y, C2));  // (d/2pi)^2
    t = fmaxf(t, 0.0f);
    float r = __builtin_amdgcn_sqrtf(t);         // d/2pi
    s += __builtin_amdgcn_sinf(r);               // v_sin_f32 (revolutions)
    c += __builtin_amdgcn_cosf(r);               // v_cos_f32
}

__global__ __launch_bounds__(256, 8) void geo_emb_kernel(
    const float* __restrict__ p0,
    const float* __restrict__ p1,
    float* __restrict__ out)
{
    const int lane = threadIdx.x & 63;
    const int wid  = (blockIdx.x << 2) | (threadIdx.x >> 6);  // 0..23999

    const bool side0 = (wid < GB * GN);
    const int i2 = side0 ? wid : wid - GB * GN;   // flat (b,row) index
    const int b  = i2 / GN;                       // magic-mul

    const float2 pr = side0 ? ((const float2*)p0)[i2]
                            : ((const float2*)p1)[i2];
    const float px = pr.x, py = pr.y;
    const float ax = -2.0f * K2 * px;
    const float ay = -2.0f * K2 * py;

    const float2* __restrict__ qp =
        ((const float2*)(side0 ? p1 : p0)) + b * GN + lane;

    float s0 = 0.f, s1 = 0.f, s2 = 0.f, s3 = 0.f;
    float c0 = 0.f, c1 = 0.f, c2 = 0.f, c3 = 0.f;

    // j = 0..39: five 8-wide batches (imm offsets 0..3584B off stepped base)
    #pragma unroll 1
    for (int j = 0; j < 40; j += 8) {
        float2 q0 = qp[0 * 64];
        float2 q1 = qp[1 * 64];
        float2 q2 = qp[2 * 64];
        float2 q3 = qp[3 * 64];
        float2 q4 = qp[4 * 64];
        float2 q5 = qp[5 * 64];
        float2 q6 = qp[6 * 64];
        float2 q7 = qp[7 * 64];
        qp += 8 * 64;
        acc2(q0, ax, ay, s0, c0);
        acc2(q1, ax, ay, s1, c1);
        acc2(q2, ax, ay, s2, c2);
        acc2(q3, ax, ay, s3, c3);
        acc2(q4, ax, ay, s0, c0);
        acc2(q5, ax, ay, s1, c1);
        acc2(q6, ax, ay, s2, c2);
        acc2(q7, ax, ay, s3, c3);
    }
    // j = 40..45: six more full chunks
    {
        float2 q0 = qp[0 * 64];
        float2 q1 = qp[1 * 64];
        float2 q2 = qp[2 * 64];
        float2 q3 = qp[3 * 64];
        float2 q4 = qp[4 * 64];
        float2 q5 = qp[5 * 64];
        qp += 6 * 64;
        acc2(q0, ax, ay, s0, c0);
        acc2(q1, ax, ay, s1, c1);
        acc2(q2, ax, ay, s2, c2);
        acc2(q3, ax, ay, s3, c3);
        acc2(q4, ax, ay, s0, c0);
        acc2(q5, ax, ay, s1, c1);
    }
    // j = 46: partners 2944..2999 (lanes 0..55)
    if (lane < 56) {
        float2 q = qp[0];
        acc2(q, ax, ay, s2, c2);
    }

    float ssum = (s0 + s1) + (s2 + s3);
    float csum = (c0 + c1) + (c2 + c3);

    #pragma unroll
    for (int off = 32; off >= 1; off >>= 1) {
        ssum += __shfl_down(ssum, off, 64);
        csum += __shfl_down(csum, off, 64);
    }

    if (lane == 0) {
        float2 res;
        res.x = px * ssum;
        res.y = py * csum;
        ((float2*)out)[wid] = res;
    }
}

extern "C" void kernel_launch(void* const* d_in, const int* in_sizes, int n_in,
                              void* d_out, int out_size, void* d_ws, size_t ws_size,
                              hipStream_t stream) {
    const float* points0 = (const float*)d_in[0];
    const float* points1 = (const float*)d_in[1];
    float* out = (float*)d_out;

    dim3 grid((2 * GB * GN) / 4);   // 6000 blocks x 4 waves = 24000 rows
    dim3 block(256);
    geo_emb_kernel<<<grid, block, 0, stream>>>(points0, points1, out);
}

// Round 7
// 80.023 us; speedup vs baseline: 1.0937x; 1.0937x over previous
//
#include <hip/hip_runtime.h>
#include <math.h>

// GeometricEmbedding: B=4, N=M=3000, d_model=2, sigma_d=1.0
// out[0..12000) float2 = p0[i] * (sum_m sin d, sum_m cos d)
// out[12000..24000)    = p1[i] * (sum_n sin d, sum_n cos d)
// d = sqrt(max(2 - 2*<p0,p1>, 0))
//
// R6 post-mortem: 4 structures all stuck at 37-40us kernel time, ~1.5x above
// the trans-pipe floor (~26.6us @ trans=16cyc/wave). Cause: ILP came from
// deeper column unrolls feeding the SAME row accumulators. This version:
// one wave owns 4 ROWS sharing one q-stream -> per q, 4 fully independent
// dot->sqrt->sin->cos chains. Row constants in SGPRs (readfirstlane).
// 6000 waves (1500 blocks), 46 full col-steps + masked tail.

#define GB 4
#define GN 3000
#define K2 0.025330295910584444f    // (1/2pi)^2
#define C2 0.050660591821168888f    // 2*(1/2pi)^2

__device__ __forceinline__ float sreg(float x) {   // pin wave-uniform to SGPR
    return __int_as_float(__builtin_amdgcn_readfirstlane(__float_as_int(x)));
}

__global__ __launch_bounds__(256, 4) void geo_emb_kernel(
    const float* __restrict__ p0,
    const float* __restrict__ p1,
    float* __restrict__ out)
{
    const int lane = threadIdx.x & 63;
    const int wid  = (blockIdx.x << 2) | (threadIdx.x >> 6);  // 0..5999 quads

    const bool side0 = (wid < 3000);
    const int quad = side0 ? wid : wid - 3000;
    const int i2   = quad << 2;               // first row (0..11996), 4 | GN
    const int b    = i2 / GN;                 // magic-mul

    const float2* __restrict__ ownp = (const float2*)(side0 ? p0 : p1);
    const float2* __restrict__ othp = (const float2*)(side0 ? p1 : p0);

    const float2 pr0 = ownp[i2 + 0];
    const float2 pr1 = ownp[i2 + 1];
    const float2 pr2 = ownp[i2 + 2];
    const float2 pr3 = ownp[i2 + 3];

    const float mm = -2.0f * K2;
    const float ax0 = sreg(mm * pr0.x), ay0 = sreg(mm * pr0.y);
    const float ax1 = sreg(mm * pr1.x), ay1 = sreg(mm * pr1.y);
    const float ax2 = sreg(mm * pr2.x), ay2 = sreg(mm * pr2.y);
    const float ax3 = sreg(mm * pr3.x), ay3 = sreg(mm * pr3.y);
    const float c2v = C2;

    float s0 = 0.f, c0 = 0.f, s1 = 0.f, c1 = 0.f;
    float s2 = 0.f, c2 = 0.f, s3 = 0.f, c3 = 0.f;

#define STEP(q) do {                                                     \
    float t0 = fmaf(ax0, (q).x, fmaf(ay0, (q).y, c2v));                  \
    float t1 = fmaf(ax1, (q).x, fmaf(ay1, (q).y, c2v));                  \
    float t2 = fmaf(ax2, (q).x, fmaf(ay2, (q).y, c2v));                  \
    float t3 = fmaf(ax3, (q).x, fmaf(ay3, (q).y, c2v));                  \
    t0 = fmaxf(t0, 0.f); t1 = fmaxf(t1, 0.f);                            \
    t2 = fmaxf(t2, 0.f); t3 = fmaxf(t3, 0.f);                            \
    float r0 = __builtin_amdgcn_sqrtf(t0);                               \
    float r1 = __builtin_amdgcn_sqrtf(t1);                               \
    float r2 = __builtin_amdgcn_sqrtf(t2);                               \
    float r3 = __builtin_amdgcn_sqrtf(t3);                               \
    s0 += __builtin_amdgcn_sinf(r0); c0 += __builtin_amdgcn_cosf(r0);    \
    s1 += __builtin_amdgcn_sinf(r1); c1 += __builtin_amdgcn_cosf(r1);    \
    s2 += __builtin_amdgcn_sinf(r2); c2 += __builtin_amdgcn_cosf(r2);    \
    s3 += __builtin_amdgcn_sinf(r3); c3 += __builtin_amdgcn_cosf(r3);    \
} while (0)

    const float2* __restrict__ qp = othp + b * GN + lane;
    float2 qA = qp[0];
    #pragma unroll 1
    for (int j = 0; j < 45; ++j) {        // compute cols lane + {0..44}*64
        float2 qB = qp[64];
        qp += 64;
        STEP(qA);
        qA = qB;
    }
    STEP(qA);                             // col lane + 45*64   (2944 total)
    if (lane < 56) {                      // cols 2944..2999
        float2 qT = qp[64];
        STEP(qT);
    }
#undef STEP

    #pragma unroll
    for (int off = 32; off >= 1; off >>= 1) {
        s0 += __shfl_down(s0, off, 64);  c0 += __shfl_down(c0, off, 64);
        s1 += __shfl_down(s1, off, 64);  c1 += __shfl_down(c1, off, 64);
        s2 += __shfl_down(s2, off, 64);  c2 += __shfl_down(c2, off, 64);
        s3 += __shfl_down(s3, off, 64);  c3 += __shfl_down(c3, off, 64);
    }

    if (lane == 0) {
        float2* o2 = (float2*)out;
        const int ob = wid << 2;          // side1 quads land at 12000+
        o2[ob + 0] = make_float2(pr0.x * s0, pr0.y * c0);
        o2[ob + 1] = make_float2(pr1.x * s1, pr1.y * c1);
        o2[ob + 2] = make_float2(pr2.x * s2, pr2.y * c2);
        o2[ob + 3] = make_float2(pr3.x * s3, pr3.y * c3);
    }
}

extern "C" void kernel_launch(void* const* d_in, const int* in_sizes, int n_in,
                              void* d_out, int out_size, void* d_ws, size_t ws_size,
                              hipStream_t stream) {
    const float* points0 = (const float*)d_in[0];
    const float* points1 = (const float*)d_in[1];
    float* out = (float*)d_out;

    dim3 grid(1500);    // 6000 waves x 4 rows = 24000 output rows
    dim3 block(256);
    geo_emb_kernel<<<grid, block, 0, stream>>>(points0, points1, out);
}